// Round 3
// baseline (198.543 us; speedup 1.0000x reference)
//
#include <hip/hip_runtime.h>

using u32 = unsigned int;
using u16 = unsigned short;

typedef __attribute__((ext_vector_type(8)))  __bf16 bf16x8;
typedef __attribute__((ext_vector_type(16))) float  f32x16;
typedef __attribute__((ext_vector_type(4)))  float  f32x4;
typedef __attribute__((ext_vector_type(4)))  int    i32x4;

__device__ __forceinline__ u32 f2bf(float f){
  u32 u = __float_as_uint(f);
  return (u + 0x7FFFu + ((u >> 16) & 1u)) >> 16;
}
__device__ __forceinline__ u32 pack2bf(float lo, float hi){
  return f2bf(lo) | (f2bf(hi) << 16);
}
__device__ __forceinline__ float bfu2f(u32 us){ return __uint_as_float(us << 16); }
__device__ __forceinline__ float lrelu(float x){ return x > 0.f ? x : 0.01f * x; }

// ---------- K0: weight [512][256] f32 -> wT [256][512] bf16 (+ init M) ----------
__global__ void k0_wt(const float* __restrict__ w, u16* __restrict__ wT, float* __restrict__ M){
  if (blockIdx.x == 0 && threadIdx.x == 0) M[0] = 0.f;
  int u = blockIdx.x * 256 + threadIdx.x;
  int k = u >> 8, n = u & 255;
  wT[(size_t)n * 512 + k] = (u16)f2bf(w[(size_t)k * 256 + n]);
}

// ---------- K1: out = x@W -> outT [256][8192] bf16, plus s1/s2/v0/v1/max-w ----------
__global__ __launch_bounds__(512, 2) void k1_gemm(const float* __restrict__ x,
    const u16* __restrict__ wT, const float* __restrict__ av, u16* __restrict__ outT,
    float* __restrict__ s1, float* __restrict__ s2,
    float* __restrict__ v0, float* __restrict__ v1, float* __restrict__ M){
  __shared__ float tb[8][32][36];
  __shared__ float afl[512];
  __shared__ float sred[2][32][17];
  __shared__ float srw[2][32];
  const int i0 = blockIdx.x * 32;
  const int tid = threadIdx.x;
  const int lane = tid & 63, wv = tid >> 6;
  const int r = lane & 31, h = lane >> 5;
  const float* xp = x + (size_t)(i0 + r) * 512 + h * 8;
  const u16*   bp = wT + (size_t)(wv * 32 + r) * 512 + h * 8;
  f32x16 acc = {};
  for (int s = 0; s < 32; ++s){
    f32x4 a0 = *(const f32x4*)xp;
    f32x4 a1 = *(const f32x4*)(xp + 4);
    i32x4 pk = { (int)pack2bf(a0[0], a0[1]), (int)pack2bf(a0[2], a0[3]),
                 (int)pack2bf(a1[0], a1[1]), (int)pack2bf(a1[2], a1[3]) };
    bf16x8 af = __builtin_bit_cast(bf16x8, pk);
    bf16x8 bf = *(const bf16x8*)bp;
    acc = __builtin_amdgcn_mfma_f32_32x32x16_bf16(af, bf, acc, 0, 0, 0);
    xp += 16; bp += 16;
  }
  #pragma unroll
  for (int re = 0; re < 16; ++re){
    int rr = (re & 3) + 8 * (re >> 2) + 4 * h;
    tb[wv][r][rr] = acc[re];
  }
  afl[tid] = av[tid];
  __syncthreads();
  // outT write
  {
    const int n2 = lane >> 1, ic = (lane & 1) * 16;
    const float* tp = &tb[wv][n2][ic];
    i32x4 w0 = { (int)pack2bf(tp[0],tp[1]),   (int)pack2bf(tp[2],tp[3]),
                 (int)pack2bf(tp[4],tp[5]),   (int)pack2bf(tp[6],tp[7]) };
    i32x4 w1 = { (int)pack2bf(tp[8],tp[9]),   (int)pack2bf(tp[10],tp[11]),
                 (int)pack2bf(tp[12],tp[13]), (int)pack2bf(tp[14],tp[15]) };
    u16* op = outT + (size_t)(wv * 32 + n2) * 8192 + i0 + ic;
    *(i32x4*)op = w0;
    *((i32x4*)op + 1) = w1;
  }
  // s-dot: s1[row] = sum_f out[row][f]*a1[f], s2 likewise (f32-accurate from acc)
  const int row = tid & 31, g = tid >> 5;
  const int w8 = g >> 1, fh = (g & 1) * 16;
  float a1c = 0.f, a2c = 0.f;
  #pragma unroll
  for (int f = 0; f < 16; ++f){
    float tv = tb[w8][fh + f][row];
    a1c = fmaf(tv, afl[w8 * 32 + fh + f], a1c);
    a2c = fmaf(tv, afl[256 + w8 * 32 + fh + f], a2c);
  }
  sred[0][row][g] = a1c; sred[1][row][g] = a2c;
  __syncthreads();
  if (tid < 64){
    int which = tid >> 5, r2 = tid & 31;
    float s = 0.f;
    #pragma unroll
    for (int g2 = 0; g2 < 16; ++g2) s += sred[which][r2][g2];
    (which ? s2 : s1)[i0 + r2] = s;
    srw[which][r2] = s;
  }
  __syncthreads();
  if (tid < 16){
    int k = (i0 >> 1) + tid;
    float sa = srw[0][2*tid], sb = srw[1][2*tid];
    float sa1 = srw[0][2*tid+1], sb1 = srw[1][2*tid+1];
    v0[k] = lrelu(sa + sb);
    v1[k] = lrelu(sa1 + sb1);
    float wv_ = fmaxf(lrelu(sa + sb1), 0.f);
    #pragma unroll
    for (int off = 8; off; off >>= 1) wv_ = fmaxf(wv_, __shfl_down(wv_, off, 16));
    if (tid == 0) atomicMax((int*)M, __float_as_int(wv_));
  }
}

// ---------- K2b2: p = exp(w - M) -> pbf (bf16), pfbot (f32 of bf16), pftop = 1 ----------
__global__ void k2b2(const float* __restrict__ s1, const float* __restrict__ s2,
    const float* __restrict__ M, u16* __restrict__ pbf,
    float* __restrict__ pftop, float* __restrict__ pfbot){
  int k = blockIdx.x * 512 + threadIdx.x;
  float m = M[0];
  float w = lrelu(s1[2*k] + s2[2*k+1]);
  float p = __expf(w - m);
  u32 pb16 = f2bf(p);
  pbf[k] = (u16)pb16;
  pfbot[k] = bfu2f(pb16);
  pftop[k] = 1.0f;
}

// ---------- K2c: out2T[n][j] = p[j&4095] * outT[n][j] ----------
__global__ void k2c_scale(const u16* __restrict__ outT, const u16* __restrict__ pbf,
                          u16* __restrict__ out2T){
  const int u = blockIdx.x * 256 + threadIdx.x;
  const int n = u >> 10;
  const int j8 = (u & 1023) * 8;
  i32x4 ov = *(const i32x4*)(outT + (size_t)n * 8192 + j8);
  i32x4 pv = *(const i32x4*)(pbf + (j8 & 4095));
  i32x4 rv;
  #pragma unroll
  for (int q = 0; q < 4; ++q){
    u32 o = (u32)ov[q], p = (u32)pv[q];
    rv[q] = (int)pack2bf(bfu2f(o & 0xFFFFu) * bfu2f(p & 0xFFFFu),
                         bfu2f(o >> 16)     * bfu2f(p >> 16));
  }
  *(i32x4*)(out2T + (size_t)n * 8192 + j8) = rv;
}

// ---------- K3: LDS-staged binary GEMM, split-K=2, 32-row tiles ----------
// grid 512: xcd=bid&7 -> half=xcd>>2, chunk c=(xcd>>1)&1, subtile=xcd&1; slot=bid>>3
// block: 32 rows x 256 feats, K-chunk 4096, 8 waves x 32 feats, K_step 128
// A staged in LDS as bf16 with XOR-swizzled 16B slots: phys = logical ^ (row&15)
// B double-buffered in REGISTERS (ping-pong) -> no vmem waits in MFMA phase.
__global__ __launch_bounds__(512, 4) void k3_main(const int* __restrict__ adj,
    const u16* __restrict__ outT, const u16* __restrict__ out2T,
    const float* __restrict__ pftop, const float* __restrict__ pfbot,
    float* __restrict__ P, float* __restrict__ pd){
  __shared__ u16 Ab[2][4096];          // [buf][32 rows][16 slots][8 u16]
  __shared__ float dred[32][17];
  const int bid = blockIdx.x;
  const int xcd = bid & 7, slot = bid >> 3;
  const int half = xcd >> 2, c = (xcd >> 1) & 1;
  const int gtile = half * 128 + slot * 2 + (xcd & 1);
  const int i0 = gtile * 32;
  const int kbase = c * 4096;
  const int pb = gtile * 2 + c;
  const u16* BT = half ? out2T : outT;
  const float* pf = half ? pfbot : pftop;
  const int tid = threadIdx.x, lane = tid & 63, wv = tid >> 6;
  const int r = lane & 31, h = lane >> 5;
  const int fb = wv * 32;
  const int srow = tid >> 4, sc = tid & 15;
  const int swz = r & 15;
  const int* aq = adj + (size_t)(i0 + srow) * 8192 + kbase + sc * 8;
  const float* pq = pf + sc * 8;
  const u16* bq = BT + (size_t)(fb + r) * 8192 + kbase + h * 8;
  u16* const wsl = &Ab[0][0] + (srow * 16 + (sc ^ (srow & 15))) * 8;
  const u16* const rsl = &Ab[0][0] + r * 128;
  f32x16 acc = {};
  float d = 0.f;
  i32x4 ar0, ar1;
  bf16x8 bA[8], bB[8];

#define PREF_A() { ar0 = __builtin_nontemporal_load((const i32x4*)aq); \
                   ar1 = __builtin_nontemporal_load((const i32x4*)aq + 1); aq += 128; }
#define PREF_B(B_) { _Pragma("unroll") for (int ks = 0; ks < 8; ++ks) \
                       B_[ks] = *(const bf16x8*)(bq + ks * 16); bq += 128; }
#define STORET(buf_) { \
  f32x4 p0 = *(const f32x4*)pq; f32x4 p1 = *(const f32x4*)(pq + 4); pq += 128; \
  d = fmaf((float)ar0[0], p0[0], d); d = fmaf((float)ar0[1], p0[1], d); \
  d = fmaf((float)ar0[2], p0[2], d); d = fmaf((float)ar0[3], p0[3], d); \
  d = fmaf((float)ar1[0], p1[0], d); d = fmaf((float)ar1[1], p1[1], d); \
  d = fmaf((float)ar1[2], p1[2], d); d = fmaf((float)ar1[3], p1[3], d); \
  i32x4 w = { \
    (int)((u32)(ar0[0] * 0x3F80) | ((u32)(ar0[1] * 0x3F8) << 20)), \
    (int)((u32)(ar0[2] * 0x3F80) | ((u32)(ar0[3] * 0x3F8) << 20)), \
    (int)((u32)(ar1[0] * 0x3F80) | ((u32)(ar1[1] * 0x3F8) << 20)), \
    (int)((u32)(ar1[2] * 0x3F80) | ((u32)(ar1[3] * 0x3F8) << 20)) }; \
  *(i32x4*)(wsl + (buf_) * 4096) = w; }
#define MFMA8(B_, buf_) { \
  const u16* rb = rsl + (buf_) * 4096; \
  _Pragma("unroll") for (int ks = 0; ks < 8; ++ks){ \
    bf16x8 av = *(const bf16x8*)(rb + (((h + 2 * ks) ^ swz) << 3)); \
    acc = __builtin_amdgcn_mfma_f32_32x32x16_bf16(av, B_[ks], acc, 0, 0, 0); } }

  // prologue: stage t=0
  PREF_A();
  PREF_B(bA);
  STORET(0);
  __syncthreads();
  for (int t = 0; t < 32; t += 2){
    // compute t (buf0, bA); prefetch+store t+1
    PREF_A();
    PREF_B(bB);
    MFMA8(bA, 0);
    STORET(1);
    __syncthreads();
    // compute t+1 (buf1, bB); prefetch+store t+2
    if (t < 30){ PREF_A(); PREF_B(bA); }
    MFMA8(bB, 1);
    if (t < 30){ STORET(0); }
    __syncthreads();
  }
#undef PREF_A
#undef PREF_B
#undef STORET
#undef MFMA8
  dred[srow][sc] = d;
  __syncthreads();
  if (tid < 32){
    float s = 0.f;
    #pragma unroll
    for (int q = 0; q < 16; ++q) s += dred[tid][q];
    pd[(size_t)pb * 32 + tid] = s;
  }
  float* Pb = P + (size_t)pb * 8192 + fb + r;
  #pragma unroll
  for (int e = 0; e < 16; ++e){
    int rr = (e & 3) + 8 * (e >> 2) + 4 * h;
    __builtin_nontemporal_store(acc[e], Pb + (size_t)rr * 256);
  }
}

// ---------- K4: combine K-split partials + softmax coeffs + sigmoid ----------
__global__ void k4_final(const float* __restrict__ P, const float* __restrict__ pd,
    const float* __restrict__ v0, const float* __restrict__ v1, float* __restrict__ out){
  const int i = blockIdx.x, n = threadIdx.x;
  const int tile = i >> 5, rloc = i & 31;
  const size_t base = (size_t)tile * 16384 + (size_t)rloc * 256 + n;
  float P0 = __builtin_nontemporal_load(P + base);
  float P1 = __builtin_nontemporal_load(P + base + 8192);
  float d0 = pd[tile * 64 + rloc];
  float d1 = pd[tile * 64 + 32 + rloc];
  float val;
  if (i < 4096){
    float va = v0[i], vb = v1[i];
    float m = fmaxf(va, vb);
    float e0 = __expf(va - m), e1 = __expf(vb - m);
    val = (e0 * P0 + e1 * P1) / (e0 * d0 + e1 * d1);
  } else {
    val = (P0 + P1) / (d0 + d1);
  }
  out[(size_t)i * 256 + n] = 1.0f / (1.0f + __expf(-val));
}

extern "C" void kernel_launch(void* const* d_in, const int* in_sizes, int n_in,
                              void* d_out, int out_size, void* d_ws, size_t ws_size,
                              hipStream_t stream)
{
  const float* x      = (const float*)d_in[0];
  const float* weight = (const float*)d_in[1];
  const float* av     = (const float*)d_in[2];
  const int*   adj    = (const int*)d_in[3];
  float* out = (float*)d_out;
  char* ws = (char*)d_ws;
  float* P     = (float*)(ws + 0);             // 16,777,216 B
  float* pd    = (float*)(ws + 16777216);      //     65,536 B
  u16*   outT  = (u16*)  (ws + 16842752);      //  4,194,304 B
  u16*   out2T = (u16*)  (ws + 21037056);      //  4,194,304 B
  u16*   wT    = (u16*)  (ws + 25231360);      //    262,144 B
  u16*   pbf   = (u16*)  (ws + 25493504);      //      8,192 B
  float* pftop = (float*)(ws + 25501696);      //     16,384 B
  float* pfbot = (float*)(ws + 25518080);      //     16,384 B
  float* s1    = (float*)(ws + 25534464);      //     32,768 B
  float* s2    = (float*)(ws + 25567232);      //     32,768 B
  float* v0    = (float*)(ws + 25600000);      //     16,384 B
  float* v1    = (float*)(ws + 25616384);      //     16,384 B
  float* M     = (float*)(ws + 25632768);      //          4 B

  k0_wt    <<<512, 256, 0, stream>>>(weight, wT, M);
  k1_gemm  <<<256, 512, 0, stream>>>(x, wT, av, outT, s1, s2, v0, v1, M);
  k2b2     <<<8, 512, 0, stream>>>(s1, s2, M, pbf, pftop, pfbot);
  k2c_scale<<<1024, 256, 0, stream>>>(outT, pbf, out2T);
  k3_main  <<<512, 512, 0, stream>>>(adj, outT, out2T, pftop, pfbot, P, pd);
  k4_final <<<8192, 256, 0, stream>>>(P, pd, v0, v1, out);
}

// Round 4
// 146.249 us; speedup vs baseline: 1.3576x; 1.3576x over previous
//
#include <hip/hip_runtime.h>

using u32 = unsigned int;
using u16 = unsigned short;

typedef __attribute__((ext_vector_type(8)))  __bf16 bf16x8;
typedef __attribute__((ext_vector_type(16))) float  f32x16;
typedef __attribute__((ext_vector_type(4)))  float  f32x4;
typedef __attribute__((ext_vector_type(4)))  int    i32x4;

__device__ __forceinline__ u32 f2bf(float f){
  u32 u = __float_as_uint(f);
  return (u + 0x7FFFu + ((u >> 16) & 1u)) >> 16;
}
__device__ __forceinline__ u32 pack2bf(float lo, float hi){
  return f2bf(lo) | (f2bf(hi) << 16);
}
__device__ __forceinline__ float bfu2f(u32 us){ return __uint_as_float(us << 16); }
__device__ __forceinline__ float lrelu(float x){ return x > 0.f ? x : 0.01f * x; }

// ---------- K0: weight [512][256] f32 -> wT [256][512] bf16 (+ init M) ----------
__global__ void k0_wt(const float* __restrict__ w, u16* __restrict__ wT, float* __restrict__ M){
  if (blockIdx.x == 0 && threadIdx.x == 0) M[0] = 0.f;
  int u = blockIdx.x * 256 + threadIdx.x;
  int k = u >> 8, n = u & 255;
  wT[(size_t)n * 512 + k] = (u16)f2bf(w[(size_t)k * 256 + n]);
}

// ---------- K1: out = x@W -> outF (MFMA-frag layout), plus s1/s2/v0/v1/max-w ----------
// outF element (k16, n, h, e) = out[i][n] with i = k16*16 + h*8 + e
__global__ __launch_bounds__(512, 2) void k1_gemm(const float* __restrict__ x,
    const u16* __restrict__ wT, const float* __restrict__ av, u16* __restrict__ outF,
    float* __restrict__ s1, float* __restrict__ s2,
    float* __restrict__ v0, float* __restrict__ v1, float* __restrict__ M){
  __shared__ float tb[8][32][36];
  __shared__ float afl[512];
  __shared__ float sred[2][32][17];
  __shared__ float srw[2][32];
  const int i0 = blockIdx.x * 32;
  const int tid = threadIdx.x;
  const int lane = tid & 63, wv = tid >> 6;
  const int r = lane & 31, h = lane >> 5;
  const float* xp = x + (size_t)(i0 + r) * 512 + h * 8;
  const u16*   bp = wT + (size_t)(wv * 32 + r) * 512 + h * 8;
  f32x16 acc = {};
  for (int s = 0; s < 32; ++s){
    f32x4 a0 = *(const f32x4*)xp;
    f32x4 a1 = *(const f32x4*)(xp + 4);
    i32x4 pk = { (int)pack2bf(a0[0], a0[1]), (int)pack2bf(a0[2], a0[3]),
                 (int)pack2bf(a1[0], a1[1]), (int)pack2bf(a1[2], a1[3]) };
    bf16x8 af = __builtin_bit_cast(bf16x8, pk);
    bf16x8 bf = *(const bf16x8*)bp;
    acc = __builtin_amdgcn_mfma_f32_32x32x16_bf16(af, bf, acc, 0, 0, 0);
    xp += 16; bp += 16;
  }
  #pragma unroll
  for (int re = 0; re < 16; ++re){
    int rr = (re & 3) + 8 * (re >> 2) + 4 * h;
    tb[wv][r][rr] = acc[re];
  }
  afl[tid] = av[tid];
  __syncthreads();
  // outF write (frag layout)
  {
    const int n2 = lane >> 1, ic = (lane & 1) * 16;
    const float* tp = &tb[wv][n2][ic];
    i32x4 w0 = { (int)pack2bf(tp[0],tp[1]),   (int)pack2bf(tp[2],tp[3]),
                 (int)pack2bf(tp[4],tp[5]),   (int)pack2bf(tp[6],tp[7]) };
    i32x4 w1 = { (int)pack2bf(tp[8],tp[9]),   (int)pack2bf(tp[10],tp[11]),
                 (int)pack2bf(tp[12],tp[13]), (int)pack2bf(tp[14],tp[15]) };
    const int n = wv * 32 + n2;
    const int k16 = (i0 + ic) >> 4;
    u16* op = outF + ((size_t)k16 * 256 + n) * 16;
    *(i32x4*)op = w0;        // h=0: i offsets 0..7
    *((i32x4*)op + 1) = w1;  // h=1: i offsets 8..15
  }
  // s-dots from f32 acc
  const int row = tid & 31, g = tid >> 5;
  const int w8 = g >> 1, fh = (g & 1) * 16;
  float a1c = 0.f, a2c = 0.f;
  #pragma unroll
  for (int f = 0; f < 16; ++f){
    float tv = tb[w8][fh + f][row];
    a1c = fmaf(tv, afl[w8 * 32 + fh + f], a1c);
    a2c = fmaf(tv, afl[256 + w8 * 32 + fh + f], a2c);
  }
  sred[0][row][g] = a1c; sred[1][row][g] = a2c;
  __syncthreads();
  if (tid < 64){
    int which = tid >> 5, r2 = tid & 31;
    float s = 0.f;
    #pragma unroll
    for (int g2 = 0; g2 < 16; ++g2) s += sred[which][r2][g2];
    (which ? s2 : s1)[i0 + r2] = s;
    srw[which][r2] = s;
  }
  __syncthreads();
  if (tid < 16){
    int k = (i0 >> 1) + tid;
    float sa = srw[0][2*tid], sb = srw[1][2*tid];
    float sa1 = srw[0][2*tid+1], sb1 = srw[1][2*tid+1];
    v0[k] = lrelu(sa + sb);
    v1[k] = lrelu(sa1 + sb1);
    float wv_ = fmaxf(lrelu(sa + sb1), 0.f);
    #pragma unroll
    for (int off = 8; off; off >>= 1) wv_ = fmaxf(wv_, __shfl_down(wv_, off, 16));
    if (tid == 0) atomicMax((int*)M, __float_as_int(wv_));
  }
}

// ---------- K2b2: p = exp(w - M) -> pbf (bf16), pfbot (f32 of bf16), pftop = 1 ----------
__global__ void k2b2(const float* __restrict__ s1, const float* __restrict__ s2,
    const float* __restrict__ M, u16* __restrict__ pbf,
    float* __restrict__ pftop, float* __restrict__ pfbot){
  int k = blockIdx.x * 512 + threadIdx.x;
  float m = M[0];
  float w = lrelu(s1[2*k] + s2[2*k+1]);
  float p = __expf(w - m);
  u32 pb16 = f2bf(p);
  pbf[k] = (u16)pb16;
  pfbot[k] = bfu2f(pb16);
  pftop[k] = 1.0f;
}

// ---------- K2c: out2F = p-scaled outF (same frag layout) ----------
__global__ void k2c_scale(const u16* __restrict__ outF, const u16* __restrict__ pbf,
                          u16* __restrict__ out2F){
  const int u = blockIdx.x * 256 + threadIdx.x;   // 0..262143, 8 elems each
  const size_t off = (size_t)u * 8;
  const int h = u & 1, k16 = u >> 9;
  const int ibase = (k16 * 16 + h * 8) & 4095;
  i32x4 ov = *(const i32x4*)(outF + off);
  i32x4 pv = *(const i32x4*)(pbf + ibase);
  i32x4 rv;
  #pragma unroll
  for (int q = 0; q < 4; ++q){
    u32 o = (u32)ov[q], p = (u32)pv[q];
    rv[q] = (int)pack2bf(bfu2f(o & 0xFFFFu) * bfu2f(p & 0xFFFFu),
                         bfu2f(o >> 16)     * bfu2f(p >> 16));
  }
  *(i32x4*)(out2F + off) = rv;
}

// ---------- K3: full-K binary GEMM, deep pipeline, raw barriers ----------
// 256 blocks x 512 thr. Block: 32 rows x 256 feats x K=8192 (64 steps of 128).
// Step s: issue adj/p(s+2), B(s+1); MFMA(s) from LDS buf + B regs; pack adj(s+1)->LDS.
__global__ __launch_bounds__(512, 2) void k3_main(const int* __restrict__ adj,
    const u16* __restrict__ outF, const u16* __restrict__ out2F,
    const float* __restrict__ pftop, const float* __restrict__ pfbot,
    const float* __restrict__ v0, const float* __restrict__ v1,
    float* __restrict__ out){
  __shared__ u16 Ab[2][4096];            // [buf][k16][h][slot^row][8] bf16, XOR-swizzled
  __shared__ float dred0[32][17];
  __shared__ float dred1[32][17];
  __shared__ float al[32], be[32];
  const int bid = blockIdx.x;
  const int xcd = bid & 7, slot = bid >> 3;
  const bool top = xcd < 4;
  const int tile = top ? (xcd * 32 + slot) : ((xcd - 4) * 32 + slot);
  const int i0 = (top ? tile : 128 + tile) * 32;
  const u16* BF = top ? outF : out2F;
  const float* pf = top ? pftop : pfbot;
  const int tid = threadIdx.x, lane = tid & 63, wv = tid >> 6;
  const int r = lane & 31, h = lane >> 5, fb = wv * 32;
  const int srow = tid >> 4, sc = tid & 15;
  const int r8 = r * 8, h8 = h * 8, h256 = h * 256;
  const int* aq0 = adj + (size_t)(i0 + srow) * 8192 + sc * 8;
  const float* pq0 = pf + sc * 8;
  const u16* bq0 = BF + (size_t)(fb + r) * 16 + h8;
  u16* const wp0 = &Ab[0][0] + sc * 256 + ((srow ^ sc) * 8);

  i32x4 aA0, aA1, aB0, aB1;
  f32x4 pA0, pA1, pB0, pB1;
  bf16x8 BA[8], BB[8];
  f32x16 acc0 = {}, acc1 = {};
  float d0 = 0.f, d1 = 0.f;

#define ADJ_ISS(A0_,A1_,P0_,P1_,S_) { \
  const int* ap_ = aq0 + (S_) * 128; \
  A0_ = __builtin_nontemporal_load((const i32x4*)ap_); \
  A1_ = __builtin_nontemporal_load((const i32x4*)(ap_ + 4)); \
  const float* pp_ = pq0 + ((S_) & 31) * 128; \
  P0_ = *(const f32x4*)pp_; P1_ = *(const f32x4*)(pp_ + 4); }

#define B_ISS(B_,S_) { const u16* bb_ = bq0 + (size_t)(S_) * 32768; \
  _Pragma("unroll") for (int ks = 0; ks < 8; ++ks) \
    B_[ks] = *(const bf16x8*)(bb_ + ks * 4096); }

#define MFMA8(B_,ACC_,BUF_) { const u16* rb_ = &Ab[BUF_][0]; \
  _Pragma("unroll") for (int ks = 0; ks < 8; ++ks){ \
    bf16x8 a_ = *(const bf16x8*)(rb_ + ks * 512 + h256 + (r8 ^ (ks * 16 + h8))); \
    ACC_ = __builtin_amdgcn_mfma_f32_32x32x16_bf16(a_, B_[ks], ACC_, 0, 0, 0); } }

#define PACKW(A0_,A1_,P0_,P1_,DD_,BUF_) { \
  DD_ = fmaf((float)A0_[0], P0_[0], DD_); DD_ = fmaf((float)A0_[1], P0_[1], DD_); \
  DD_ = fmaf((float)A0_[2], P0_[2], DD_); DD_ = fmaf((float)A0_[3], P0_[3], DD_); \
  DD_ = fmaf((float)A1_[0], P1_[0], DD_); DD_ = fmaf((float)A1_[1], P1_[1], DD_); \
  DD_ = fmaf((float)A1_[2], P1_[2], DD_); DD_ = fmaf((float)A1_[3], P1_[3], DD_); \
  i32x4 w_ = { \
    (int)((u32)(A0_[0] * 0x3F80) | ((u32)(A0_[1] * 0x3F8) << 20)), \
    (int)((u32)(A0_[2] * 0x3F80) | ((u32)(A0_[3] * 0x3F8) << 20)), \
    (int)((u32)(A1_[0] * 0x3F80) | ((u32)(A1_[1] * 0x3F8) << 20)), \
    (int)((u32)(A1_[2] * 0x3F80) | ((u32)(A1_[3] * 0x3F8) << 20)) }; \
  *(i32x4*)(wp0 + (BUF_) * 4096) = w_; }

#define KBAR() { asm volatile("s_waitcnt lgkmcnt(0)" ::: "memory"); \
  __builtin_amdgcn_s_barrier(); asm volatile("" ::: "memory"); }

#define STEP2(S_, ACC_, DPA_, DPB_) { \
    ADJ_ISS(aA0,aA1,pA0,pA1, (S_)+2); \
    B_ISS(BB, (S_)+1); \
    MFMA8(BA, ACC_, 0); \
    PACKW(aB0,aB1,pB0,pB1, DPA_, 1); \
    KBAR(); \
    ADJ_ISS(aB0,aB1,pB0,pB1, (S_)+3); \
    B_ISS(BA, (S_)+2); \
    MFMA8(BB, ACC_, 1); \
    PACKW(aA0,aA1,pA0,pA1, DPB_, 0); \
    KBAR(); }

  // prologue: adj(0)->A, adj(1)->B, B(0)->BA, pack(0)->buf0
  ADJ_ISS(aA0, aA1, pA0, pA1, 0);
  ADJ_ISS(aB0, aB1, pB0, pB1, 1);
  B_ISS(BA, 0);
  PACKW(aA0, aA1, pA0, pA1, d0, 0);
  KBAR();
  #pragma unroll 1
  for (int s = 0; s < 30; s += 2) STEP2(s, acc0, d0, d0);     // MFMA 0..29, pack 1..30
  STEP2(30, acc0, d0, d1);                                     // MFMA 30,31; pack 31->d0, 32->d1
  #pragma unroll 1
  for (int s = 32; s < 62; s += 2) STEP2(s, acc1, d1, d1);    // MFMA 32..61, pack 33..62
  // tail: MFMA 62,63; pack(63)
  B_ISS(BB, 63);
  MFMA8(BA, acc1, 0);
  PACKW(aB0, aB1, pB0, pB1, d1, 1);
  KBAR();
  MFMA8(BB, acc1, 1);

#undef ADJ_ISS
#undef B_ISS
#undef MFMA8
#undef PACKW
#undef STEP2

  // ---- epilogue ----
  dred0[srow][sc] = d0;
  dred1[srow][sc] = d1;
  KBAR();
  if (tid < 32){
    float D0 = 0.f, D1 = 0.f;
    #pragma unroll
    for (int q = 0; q < 16; ++q){ D0 += dred0[tid][q]; D1 += dred1[tid][q]; }
    float A_, B_;
    if (top){
      float va = v0[i0 + tid], vb = v1[i0 + tid];
      float m = fmaxf(va, vb);
      float e0 = __expf(va - m), e1 = __expf(vb - m);
      float D = e0 * D0 + e1 * D1;
      A_ = e0 / D; B_ = e1 / D;
    } else {
      float D = D0 + D1;
      A_ = 1.0f / D; B_ = A_;
    }
    al[tid] = A_; be[tid] = B_;
  }
  KBAR();
#undef KBAR
  float* ob = out + (size_t)i0 * 256 + fb + r;
  #pragma unroll
  for (int e = 0; e < 16; ++e){
    int rr = (e & 3) + 8 * (e >> 2) + 4 * h;
    float val = al[rr] * acc0[e] + be[rr] * acc1[e];
    float sg = 1.0f / (1.0f + __expf(-val));
    __builtin_nontemporal_store(sg, ob + (size_t)rr * 256);
  }
}

extern "C" void kernel_launch(void* const* d_in, const int* in_sizes, int n_in,
                              void* d_out, int out_size, void* d_ws, size_t ws_size,
                              hipStream_t stream)
{
  const float* x      = (const float*)d_in[0];
  const float* weight = (const float*)d_in[1];
  const float* av     = (const float*)d_in[2];
  const int*   adj    = (const int*)d_in[3];
  float* out = (float*)d_out;
  char* ws = (char*)d_ws;
  u16*   outF  = (u16*)  (ws + 0);             //  4,194,304 B
  u16*   out2F = (u16*)  (ws + 4194304);       //  4,194,304 B
  u16*   wT    = (u16*)  (ws + 8388608);       //    262,144 B
  u16*   pbf   = (u16*)  (ws + 8650752);       //      8,192 B
  float* pftop = (float*)(ws + 8658944);       //     16,384 B
  float* pfbot = (float*)(ws + 8675328);       //     16,384 B
  float* s1    = (float*)(ws + 8691712);       //     32,768 B
  float* s2    = (float*)(ws + 8724480);       //     32,768 B
  float* v0    = (float*)(ws + 8757248);       //     16,384 B
  float* v1    = (float*)(ws + 8773632);       //     16,384 B
  float* M     = (float*)(ws + 8790016);       //          4 B

  k0_wt    <<<512, 256, 0, stream>>>(weight, wT, M);
  k1_gemm  <<<256, 512, 0, stream>>>(x, wT, av, outF, s1, s2, v0, v1, M);
  k2b2     <<<8, 512, 0, stream>>>(s1, s2, M, pbf, pftop, pfbot);
  k2c_scale<<<1024, 256, 0, stream>>>(outF, pbf, out2F);
  k3_main  <<<256, 512, 0, stream>>>(adj, outF, out2F, pftop, pfbot, v0, v1, out);
}